// Round 1
// baseline (756.714 us; speedup 1.0000x reference)
//
#include <hip/hip_runtime.h>
#include <hip/hip_bf16.h>
#include <math.h>

#define DEV __device__ __forceinline__

#define BB 2
#define VV 6
#define CC 128
#define NQ 1200
#define HH 8
#define PTSN 4
#define FFND 256
#define LVLSN 4
#define LTOT 29750
#define NROWS (BB*NQ)

__constant__ int c_W[4] = {200,100,50,25};
__constant__ int c_H[4] = {112,56,28,14};
__constant__ int c_S[4] = {0,22400,28000,29400};

DEV float bflo(unsigned u){ union{unsigned i; float f;}x; x.i = u<<16; return x.f; }
DEV float bfhi(unsigned u){ union{unsigned i; float f;}x; x.i = u&0xffff0000u; return x.f; }
DEV unsigned short f2bf(float f){ union{float f; unsigned i;}x; x.f=f; unsigned i=x.i;
  return (unsigned short)((i + 0x7fffu + ((i>>16)&1u))>>16); }
DEV float sigm(float z){ return 1.f/(1.f+__expf(-z)); }

// ---------------- counts ----------------
__global__ void k_counts(const int* __restrict__ view, int* __restrict__ counts){
  int b = blockIdx.x;
  __shared__ int c[VV];
  if(threadIdx.x < VV) c[threadIdx.x]=0;
  __syncthreads();
  for(int n=threadIdx.x;n<NQ;n+=blockDim.x) atomicAdd(&c[view[b*NQ+n]],1);
  __syncthreads();
  if(threadIdx.x < VV) counts[b*VV+threadIdx.x]=c[threadIdx.x];
}

// ---------------- x transpose + qpe MLP ----------------
__global__ void k_prep(const float* __restrict__ iqf, const float* __restrict__ pos,
                       const float* __restrict__ w1, const float* __restrict__ b1,
                       const float* __restrict__ w2, const float* __restrict__ b2,
                       float* __restrict__ x, float* __restrict__ qpe){
  int row = blockIdx.x; int b = row/NQ, n = row%NQ;
  int t = threadIdx.x;
  __shared__ float hid[128];
  float p0 = pos[row*2+0], p1 = pos[row*2+1];
  hid[t] = fmaxf(p0*w1[t] + p1*w1[128+t] + b1[t], 0.f);
  x[(size_t)row*128 + t] = iqf[(size_t)b*CC*NQ + (size_t)t*NQ + n];
  __syncthreads();
  float acc = b2[t];
  #pragma unroll 4
  for(int c=0;c<128;c++) acc += hid[c]*w2[c*128 + t];
  qpe[(size_t)row*128+t] = acc;
}

// ---------------- kpe MLP + @d_val_w + bias -> kvpe (bf16) ----------------
__global__ void k_kvpe(const float* __restrict__ kpos,
                       const float* __restrict__ cw1, const float* __restrict__ cb1,
                       const float* __restrict__ cw2, const float* __restrict__ cb2,
                       const float* __restrict__ vw, const float* __restrict__ vb,
                       unsigned short* __restrict__ kvpe){
  int r0 = blockIdx.x*16; int t = threadIdx.x;
  __shared__ float hid[16][128];
  __shared__ float kpe[16][128];
  int d = t&127;
  for(int r = (t>>7); r<16; r+=2){
    int row = r0 + r; float p0=0.f,p1=0.f;
    if(row < LTOT){ p0 = kpos[row*2]; p1 = kpos[row*2+1]; }
    hid[r][d] = fmaxf(p0*cw1[d] + p1*cw1[128+d] + cb1[d], 0.f);
  }
  __syncthreads();
  int rb = (t>>7)*8;
  float acc[8];
  #pragma unroll
  for(int i=0;i<8;i++) acc[i] = cb2[d];
  #pragma unroll 4
  for(int c=0;c<128;c++){ float wv = cw2[c*128+d];
    #pragma unroll
    for(int i=0;i<8;i++) acc[i] += hid[rb+i][c]*wv; }
  #pragma unroll
  for(int i=0;i<8;i++) kpe[rb+i][d] = acc[i];
  __syncthreads();
  #pragma unroll
  for(int i=0;i<8;i++) acc[i] = vb[d];
  #pragma unroll 4
  for(int c=0;c<128;c++){ float wv = vw[c*128+d];
    #pragma unroll
    for(int i=0;i<8;i++) acc[i] += kpe[rb+i][c]*wv; }
  #pragma unroll
  for(int i=0;i<8;i++){ int row = r0+rb+i; if(row<LTOT) kvpe[(size_t)row*128+d] = f2bf(acc[i]); }
}

// ---------------- value projection GEMM (VALU, bf16 W in LDS) ----------------
__global__ void __launch_bounds__(256) k_value(const float* __restrict__ feat, int HW, int startL,
                        const unsigned short* __restrict__ kvpe, const float* __restrict__ vw,
                        unsigned short* __restrict__ value){
  int bv = blockIdx.y;
  int l0 = blockIdx.x*128;
  int t = threadIdx.x;
  __shared__ unsigned short w_sb[128*128]; // bf16 W  32KB
  __shared__ float a_s[16*128];            // f32 A chunk 8KB
  for(int i=t;i<128*128;i+=256) w_sb[i] = f2bf(vw[i]);
  int wave = t>>6, lane = t&63;
  int wl = wave>>1, wd = wave&1;
  int lgrp = lane>>3, dgrp = lane&7;
  int lsub = wl*64 + lgrp*8;
  int dsub = wd*64 + dgrp*8;
  float acc[8][8];
  #pragma unroll
  for(int i=0;i<8;i++)
    #pragma unroll
    for(int j=0;j<8;j++) acc[i][j]=0.f;
  const float* fbase = feat + (size_t)bv*128*(size_t)HW;
  for(int cc=0; cc<128; cc+=16){
    __syncthreads();
    for(int i=t;i<16*128;i+=256){
      int c=i>>7, l=i&127;
      int gl = l0+l;
      a_s[c*128+l] = (gl<HW) ? fbase[(size_t)(cc+c)*HW + gl] : 0.f;
    }
    __syncthreads();
    #pragma unroll
    for(int c=0;c<16;c++){
      float4 a0 = *reinterpret_cast<const float4*>(&a_s[c*128+lsub]);
      float4 a1 = *reinterpret_cast<const float4*>(&a_s[c*128+lsub+4]);
      uint4 u = *reinterpret_cast<const uint4*>(&w_sb[(cc+c)*128 + dsub]);
      float av[8] = {a0.x,a0.y,a0.z,a0.w,a1.x,a1.y,a1.z,a1.w};
      float wv[8] = {bflo(u.x),bfhi(u.x),bflo(u.y),bfhi(u.y),bflo(u.z),bfhi(u.z),bflo(u.w),bfhi(u.w)};
      #pragma unroll
      for(int i=0;i<8;i++)
        #pragma unroll
        for(int j=0;j<8;j++) acc[i][j] += av[i]*wv[j];
    }
  }
  #pragma unroll
  for(int i=0;i<8;i++){
    int gl = l0 + lsub + i;
    if(gl >= HW) continue;
    size_t orow = (size_t)bv*LTOT + startL + gl;
    uint4 ku = *reinterpret_cast<const uint4*>(kvpe + (size_t)(startL+gl)*CC + dsub);
    float kv[8] = {bflo(ku.x),bfhi(ku.x),bflo(ku.y),bfhi(ku.y),bflo(ku.z),bfhi(ku.z),bflo(ku.w),bfhi(ku.w)};
    unsigned short o8[8];
    #pragma unroll
    for(int j=0;j<8;j++) o8[j] = f2bf(acc[i][j] + kv[j]);
    uint4 pu;
    pu.x = (unsigned)o8[0] | ((unsigned)o8[1]<<16);
    pu.y = (unsigned)o8[2] | ((unsigned)o8[3]<<16);
    pu.z = (unsigned)o8[4] | ((unsigned)o8[5]<<16);
    pu.w = (unsigned)o8[6] | ((unsigned)o8[7]<<16);
    *reinterpret_cast<uint4*>(value + orow*CC + dsub) = pu;
  }
}

// ---------------- generic R-row batched matvec ----------------
template<int K, int N, int R, bool RELU>
__global__ void k_matvec(const float* __restrict__ in, const float* __restrict__ in2,
                         const float* __restrict__ W, const float* __restrict__ bias,
                         float* __restrict__ out, int nrows){
  int r0 = blockIdx.x*R; int d = threadIdx.x;
  __shared__ float s_in[R][K];
  for(int i=d;i<R*K;i+=N){
    int r=i/K, c=i%K; int row=r0+r;
    float v=0.f;
    if(row<nrows){ v = in[(size_t)row*K+c]; if(in2) v += in2[(size_t)row*K+c]; }
    s_in[r][c]=v;
  }
  __syncthreads();
  float acc[R];
  #pragma unroll
  for(int r=0;r<R;r++) acc[r]=bias[d];
  #pragma unroll 4
  for(int c=0;c<K;c++){ float wv = W[(size_t)c*N+d];
    #pragma unroll
    for(int r=0;r<R;r++) acc[r] += s_in[r][c]*wv; }
  #pragma unroll
  for(int r=0;r<R;r++){
    int row=r0+r;
    if(row<nrows){ float v=acc[r]; if(RELU) v=fmaxf(v,0.f); out[(size_t)row*N+d]=v; }
  }
}

// ---------------- masked self-attention (online softmax) ----------------
#define QT 64
#define KT 256
__global__ void k_attn(const float* __restrict__ qkv, const int* __restrict__ view,
                       float* __restrict__ att){
  int qt = blockIdx.x, h = blockIdx.y, b = blockIdx.z;
  int n0 = qt*QT;
  int t = threadIdx.x;
  __shared__ float q_s[QT][17];
  __shared__ float k_s[KT][16];
  __shared__ float v_s[KT][16];
  __shared__ int qv_s[QT];
  __shared__ int kv_s[KT];
  __shared__ float red[4][QT][18];
  for(int i=t;i<QT*16;i+=256){ int r=i>>4,c=i&15; int n=n0+r;
    q_s[r][c] = (n<NQ)? qkv[((size_t)b*NQ+n)*384 + h*16 + c] : 0.f; }
  for(int i=t;i<QT;i+=256){ int n=n0+i; qv_s[i] = (n<NQ)? view[b*NQ+n] : -1; }
  __syncthreads();
  int qi = t&63, sub = t>>6;
  int myview = qv_s[qi];
  float m = -1e30f, s = 0.f, acc[16];
  #pragma unroll
  for(int c=0;c<16;c++) acc[c]=0.f;
  for(int m0=0; m0<NQ; m0+=KT){
    __syncthreads();
    int kn = NQ-m0; if(kn>KT) kn=KT;
    for(int i=t;i<KT*16;i+=256){ int r=i>>4,c=i&15;
      float kv=0.f, vv=0.f;
      if(r<kn){ size_t base=((size_t)b*NQ+m0+r)*384 + h*16 + c;
        kv = qkv[base+128]; vv = qkv[base+256]; }
      k_s[r][c]=kv; v_s[r][c]=vv; }
    for(int i=t;i<KT;i+=256){ kv_s[i] = (i<kn)? view[b*NQ+m0+i] : -12345; }
    __syncthreads();
    for(int mm=sub; mm<kn; mm+=4){
      if(kv_s[mm]!=myview) continue;
      float l=0.f;
      #pragma unroll
      for(int c=0;c<16;c++) l += q_s[qi][c]*k_s[mm][c];
      l *= 0.25f;
      float newm = fmaxf(m,l);
      float e = __expf(l - newm);
      if(newm > m){
        float rr = __expf(m - newm);
        s *= rr;
        #pragma unroll
        for(int c=0;c<16;c++) acc[c]*=rr;
        m = newm;
      }
      s += e;
      #pragma unroll
      for(int c=0;c<16;c++) acc[c] += e*v_s[mm][c];
    }
  }
  red[sub][qi][0]=m; red[sub][qi][1]=s;
  #pragma unroll
  for(int c=0;c<16;c++) red[sub][qi][2+c]=acc[c];
  __syncthreads();
  if(sub==0){
    float M=-1e30f;
    #pragma unroll
    for(int j=0;j<4;j++) M=fmaxf(M,red[j][qi][0]);
    float S=0.f; float o[16];
    #pragma unroll
    for(int c=0;c<16;c++) o[c]=0.f;
    #pragma unroll
    for(int j=0;j<4;j++){ float e=__expf(red[j][qi][0]-M); S += e*red[j][qi][1];
      #pragma unroll
      for(int c=0;c<16;c++) o[c] += e*red[j][qi][2+c]; }
    int n=n0+qi;
    if(n<NQ){ float inv = 1.f/S;
      #pragma unroll
      for(int c=0;c<16;c++) att[((size_t)b*NQ+n)*128 + h*16 + c] = o[c]*inv; }
  }
}

// ---------------- proj + residual + LN (optional qc=ln_out+qpe) ----------------
template<bool WQC>
__global__ void k_proj_ln(const float* __restrict__ in, const float* __restrict__ W,
                          const float* __restrict__ bias, const float* __restrict__ resid,
                          const float* __restrict__ g, const float* __restrict__ bb,
                          const float* __restrict__ qpe, float* __restrict__ xout,
                          float* __restrict__ qc){
  int r0 = blockIdx.x*8; int d = threadIdx.x;
  __shared__ float s_in[8][128];
  __shared__ float s_m[8][2][2];
  for(int i=d;i<8*128;i+=128){ int r=i>>7, c=i&127; s_in[r][c] = in[(size_t)(r0+r)*128 + c]; }
  __syncthreads();
  float acc[8];
  #pragma unroll
  for(int r=0;r<8;r++) acc[r]=bias[d];
  #pragma unroll 4
  for(int c=0;c<128;c++){ float wv = W[c*128+d];
    #pragma unroll
    for(int r=0;r<8;r++) acc[r] += s_in[r][c]*wv; }
  float v[8];
  int lane = d&63, wid = d>>6;
  #pragma unroll
  for(int r=0;r<8;r++){
    v[r] = acc[r] + resid[(size_t)(r0+r)*128 + d];
    float s1=v[r], s2=v[r]*v[r];
    for(int o=32;o>0;o>>=1){ s1 += __shfl_down(s1,o); s2 += __shfl_down(s2,o); }
    if(lane==0){ s_m[r][wid][0]=s1; s_m[r][wid][1]=s2; }
  }
  __syncthreads();
  #pragma unroll
  for(int r=0;r<8;r++){
    float S1=s_m[r][0][0]+s_m[r][1][0], S2=s_m[r][0][1]+s_m[r][1][1];
    float mean=S1*(1.f/128.f), var=S2*(1.f/128.f)-mean*mean;
    float rs=rsqrtf(var+1e-5f);
    float o=(v[r]-mean)*rs*g[d]+bb[d];
    xout[(size_t)(r0+r)*128+d]=o;
    if(WQC) qc[(size_t)(r0+r)*128+d]=o+qpe[(size_t)(r0+r)*128+d];
  }
}

// ---------------- attn-weight matvec + per-head softmax(16) ----------------
__global__ void k_aw(const float* __restrict__ qc, const float* __restrict__ W,
                     const float* __restrict__ bias, float* __restrict__ aw){
  int r0 = blockIdx.x*8; int d = threadIdx.x;
  __shared__ float s_in[8][128];
  __shared__ float s_out[8][130];
  for(int i=d;i<8*128;i+=128){ int r=i>>7, c=i&127; s_in[r][c]=qc[(size_t)(r0+r)*128+c]; }
  __syncthreads();
  float acc[8];
  #pragma unroll
  for(int r=0;r<8;r++) acc[r]=bias[d];
  #pragma unroll 4
  for(int c=0;c<128;c++){ float wv = W[c*128+d];
    #pragma unroll
    for(int r=0;r<8;r++) acc[r] += s_in[r][c]*wv; }
  #pragma unroll
  for(int r=0;r<8;r++) s_out[r][d]=acc[r];
  __syncthreads();
  if(d < 64){
    int r = d>>3, h = d&7;
    float mx=-1e30f;
    #pragma unroll
    for(int i=0;i<16;i++) mx = fmaxf(mx, s_out[r][h*16+i]);
    float e[16]; float sm=0.f;
    #pragma unroll
    for(int i=0;i<16;i++){ e[i]=__expf(s_out[r][h*16+i]-mx); sm+=e[i]; }
    float inv = 1.f/sm;
    #pragma unroll
    for(int i=0;i<16;i++) aw[(size_t)(r0+r)*128 + h*16+i] = e[i]*inv;
  }
}

// ---------------- deformable bilinear sampling ----------------
__global__ void k_sample(const float* __restrict__ qpos, const int* __restrict__ view,
                         const float* __restrict__ offb, const float* __restrict__ awb,
                         const unsigned short* __restrict__ value, float* __restrict__ ca){
  int n = blockIdx.x, b = blockIdx.y;
  size_t row = (size_t)b*NQ + n;
  int t = threadIdx.x;
  int h = t>>4, lp = t&15, lvl = lp>>2;
  float rx = sigm(qpos[row*2]), ry = sigm(qpos[row*2+1]);
  int vw = view[row];
  int w = c_W[lvl], hh = c_H[lvl];
  float ox = offb[row*256 + t*2], oy = offb[row*256 + t*2+1];
  float a = awb[row*128 + t];
  float lx = rx*(float)w + ox - 0.5f;
  float ly = ry*(float)hh + oy - 0.5f;
  float x0f = floorf(lx), y0f = floorf(ly);
  float fx = lx - x0f, fy = ly - y0f;
  int x0 = (int)x0f, y0 = (int)y0f;
  float samp[16];
  #pragma unroll
  for(int c=0;c<16;c++) samp[c]=0.f;
  size_t brow = ((size_t)(b*VV + vw))*LTOT + c_S[lvl];
  #pragma unroll
  for(int dy=0;dy<2;dy++){
    #pragma unroll
    for(int dx=0;dx<2;dx++){
      int xi=x0+dx, yi=y0+dy;
      if(xi<0||xi>=w||yi<0||yi>=hh) continue;
      float wt = (dx?fx:(1.f-fx))*(dy?fy:(1.f-fy));
      const uint4* vp = reinterpret_cast<const uint4*>(value + (brow + (size_t)yi*w + xi)*CC + h*16);
      uint4 u0 = vp[0], u1 = vp[1];
      samp[0] += wt*bflo(u0.x); samp[1] += wt*bfhi(u0.x);
      samp[2] += wt*bflo(u0.y); samp[3] += wt*bfhi(u0.y);
      samp[4] += wt*bflo(u0.z); samp[5] += wt*bfhi(u0.z);
      samp[6] += wt*bflo(u0.w); samp[7] += wt*bfhi(u0.w);
      samp[8] += wt*bflo(u1.x); samp[9] += wt*bfhi(u1.x);
      samp[10]+= wt*bflo(u1.y); samp[11]+= wt*bfhi(u1.y);
      samp[12]+= wt*bflo(u1.z); samp[13]+= wt*bfhi(u1.z);
      samp[14]+= wt*bflo(u1.w); samp[15]+= wt*bfhi(u1.w);
    }
  }
  __shared__ float sred[128][17];
  #pragma unroll
  for(int c=0;c<16;c++) sred[t][c] = a*samp[c];
  __syncthreads();
  int h2=t>>4, c2=t&15;
  float sum=0.f;
  #pragma unroll
  for(int j=0;j<16;j++) sum += sred[h2*16+j][c2];
  ca[row*128 + t] = sum;
}

// ---------------- FFN2 + LN3 + valid-zero + out0 transpose ----------------
__global__ void k_ffn2_ln3(const float* __restrict__ hin, const float* __restrict__ W,
                           const float* __restrict__ bias, const float* __restrict__ resid,
                           const float* __restrict__ g, const float* __restrict__ bb,
                           const int* __restrict__ counts, const int* __restrict__ view,
                           float* __restrict__ xf, float* __restrict__ out0){
  int r0 = blockIdx.x*8; int d = threadIdx.x;
  __shared__ float s_in[8][256];
  __shared__ float s_m[8][2][2];
  for(int i=d;i<8*256;i+=128){ int r=i>>8, c=i&255; s_in[r][c]=hin[(size_t)(r0+r)*256+c]; }
  __syncthreads();
  float acc[8];
  #pragma unroll
  for(int r=0;r<8;r++) acc[r]=bias[d];
  #pragma unroll 4
  for(int c=0;c<256;c++){ float wv = W[c*128+d];
    #pragma unroll
    for(int r=0;r<8;r++) acc[r] += s_in[r][c]*wv; }
  float v[8];
  int lane = d&63, wid = d>>6;
  #pragma unroll
  for(int r=0;r<8;r++){
    v[r] = acc[r] + resid[(size_t)(r0+r)*128 + d];
    float s1=v[r], s2=v[r]*v[r];
    for(int o=32;o>0;o>>=1){ s1 += __shfl_down(s1,o); s2 += __shfl_down(s2,o); }
    if(lane==0){ s_m[r][wid][0]=s1; s_m[r][wid][1]=s2; }
  }
  __syncthreads();
  #pragma unroll
  for(int r=0;r<8;r++){
    float S1=s_m[r][0][0]+s_m[r][1][0], S2=s_m[r][0][1]+s_m[r][1][1];
    float mean=S1*(1.f/128.f), var=S2*(1.f/128.f)-mean*mean;
    float rs=rsqrtf(var+1e-5f);
    float o=(v[r]-mean)*rs*g[d]+bb[d];
    int row=r0+r; int b=row/NQ, n=row%NQ;
    bool val = counts[b*VV + view[row]] > 1;
    float oz = val ? o : 0.f;
    xf[(size_t)row*128+d]=oz;
    out0[((size_t)b*CC + d)*NQ + n]=oz;
  }
}

// ---------------- prediction head ----------------
__global__ void k_head(const float* __restrict__ xf, const float* __restrict__ pos,
                       const float* __restrict__ w1, const float* __restrict__ b1,
                       const float* __restrict__ w2, const float* __restrict__ b2,
                       float* __restrict__ dout){
  int row = blockIdx.x; int b=row/NQ, n=row%NQ; int t=threadIdx.x;
  __shared__ float xs[128];
  __shared__ float hid[128];
  __shared__ float res[6];
  xs[t] = xf[(size_t)row*128+t];
  __syncthreads();
  float a = b1[t];
  #pragma unroll 4
  for(int c=0;c<128;c++) a += xs[c]*w1[c*128+t];
  hid[t]=fmaxf(a,0.f);
  __syncthreads();
  if(t<6){ float a2=b2[t];
    #pragma unroll 4
    for(int c=0;c<128;c++) a2 += hid[c]*w2[c*6+t];
    res[t]=a2; }
  __syncthreads();
  if(t==0){
    const int O1 = BB*CC*NQ;            // 307200
    const int O2 = O1 + BB*NQ*2;        // 312000
    const int O3 = O2 + BB*2*NQ;        // 316800
    const int O4 = O3 + BB*4*NQ;        // 326400
    float p0=pos[row*2], p1=pos[row*2+1];
    float cr0 = res[0]+p0, cr1 = res[1]+p1;
    dout[O1 + row*2]   = cr0;
    dout[O1 + row*2+1] = cr1;
    float cen0 = sigm(cr0), cen1 = sigm(cr1);
    dout[O2 + (b*2+0)*NQ + n] = cen0;
    dout[O2 + (b*2+1)*NQ + n] = cen1;
    float f0=sigm(res[2]), f1=sigm(res[3]), f2=sigm(res[4]), f3=sigm(res[5]);
    dout[O3 + (b*4+0)*NQ + n] = f0;
    dout[O3 + (b*4+1)*NQ + n] = f1;
    dout[O3 + (b*4+2)*NQ + n] = f2;
    dout[O3 + (b*4+3)*NQ + n] = f3;
    float bw=f0+f2, bh=f1+f3;
    float cx=(2.f*cen0 - f0 + f2)*0.5f;
    float cy=(2.f*cen1 - f1 + f3)*0.5f;
    dout[O4 + (b*4+0)*NQ + n] = cx;
    dout[O4 + (b*4+1)*NQ + n] = cy;
    dout[O4 + (b*4+2)*NQ + n] = bw;
    dout[O4 + (b*4+3)*NQ + n] = bh;
  }
}

extern "C" void kernel_launch(void* const* d_in, const int* in_sizes, int n_in,
                              void* d_out, int out_size, void* d_ws, size_t ws_size,
                              hipStream_t stream){
  (void)in_sizes; (void)n_in; (void)out_size; (void)ws_size;
  const float* in_iqf  = (const float*)d_in[0];
  const float* in_qpos = (const float*)d_in[1];
  const float* in_feat[4] = {(const float*)d_in[2],(const float*)d_in[3],(const float*)d_in[4],(const float*)d_in[5]};
  const float* in_kpos = (const float*)d_in[6];
  const float* sp_w1=(const float*)d_in[7], *sp_b1=(const float*)d_in[8], *sp_w2=(const float*)d_in[9], *sp_b2=(const float*)d_in[10];
  const float* cp_w1=(const float*)d_in[11], *cp_b1=(const float*)d_in[12], *cp_w2=(const float*)d_in[13], *cp_b2=(const float*)d_in[14];
  const float* sa_wqkv=(const float*)d_in[15], *sa_bqkv=(const float*)d_in[16], *sa_wo=(const float*)d_in[17], *sa_bo=(const float*)d_in[18];
  const float* ln1_g=(const float*)d_in[19], *ln1_b=(const float*)d_in[20];
  const float* dvw=(const float*)d_in[21], *dvb=(const float*)d_in[22];
  const float* dow=(const float*)d_in[23], *dob=(const float*)d_in[24];
  const float* daw=(const float*)d_in[25], *dab=(const float*)d_in[26];
  const float* dOw=(const float*)d_in[27], *dOb=(const float*)d_in[28];
  const float* ln2_g=(const float*)d_in[29], *ln2_b=(const float*)d_in[30];
  const float* fw1=(const float*)d_in[31], *fb1=(const float*)d_in[32], *fw2=(const float*)d_in[33], *fb2=(const float*)d_in[34];
  const float* ln3_g=(const float*)d_in[35], *ln3_b=(const float*)d_in[36];
  const float* pw1=(const float*)d_in[37], *pb1=(const float*)d_in[38], *pw2=(const float*)d_in[39], *pb2=(const float*)d_in[40];
  const int* in_view = (const int*)d_in[41];
  float* out = (float*)d_out;

  char* ws = (char*)d_ws;
  unsigned short* value = (unsigned short*)ws;                       // 91,392,000 B
  unsigned short* kvpe  = (unsigned short*)(ws + 91392000);          //  7,616,000 B
  float* f = (float*)(ws + 91392000 + 7616000);
  float* qpe  = f;               // 307200
  float* x    = f + 307200;      // 307200
  float* qkv  = f + 614400;      // 921600
  float* att  = f + 1536000;     // 307200
  float* qc   = f + 1843200;     // 307200
  float* offb = f + 2150400;     // 614400
  float* awb  = f + 2764800;     // 307200
  float* ca   = f + 3072000;     // 307200
  float* ffnh = f + 3379200;     // 614400
  float* xf   = f + 3993600;     // 307200
  int* counts = (int*)(f + 4300800);

  static const int HWs[4]    = {22400, 5600, 1400, 350};
  static const int STARTSh[4]= {0, 22400, 28000, 29400};

  k_counts<<<dim3(BB),dim3(256),0,stream>>>(in_view, counts);
  k_prep<<<dim3(NROWS),dim3(128),0,stream>>>(in_iqf,in_qpos,sp_w1,sp_b1,sp_w2,sp_b2,x,qpe);
  k_kvpe<<<dim3((LTOT+15)/16),dim3(256),0,stream>>>(in_kpos,cp_w1,cp_b1,cp_w2,cp_b2,dvw,dvb,kvpe);
  for(int l=0;l<4;l++){
    k_value<<<dim3((HWs[l]+127)/128, BB*VV),dim3(256),0,stream>>>(in_feat[l],HWs[l],STARTSh[l],kvpe,dvw,value);
  }
  k_matvec<128,384,8,false><<<dim3(NROWS/8),dim3(384),0,stream>>>(x,qpe,sa_wqkv,sa_bqkv,qkv,NROWS);
  k_attn<<<dim3((NQ+QT-1)/QT,HH,BB),dim3(256),0,stream>>>(qkv,in_view,att);
  k_proj_ln<true><<<dim3(NROWS/8),dim3(128),0,stream>>>(att,sa_wo,sa_bo,x,ln1_g,ln1_b,qpe,x,qc);
  k_matvec<128,256,8,false><<<dim3(NROWS/8),dim3(256),0,stream>>>(qc,nullptr,dow,dob,offb,NROWS);
  k_aw<<<dim3(NROWS/8),dim3(128),0,stream>>>(qc,daw,dab,awb);
  k_sample<<<dim3(NQ,BB),dim3(128),0,stream>>>(in_qpos,in_view,offb,awb,value,ca);
  k_proj_ln<false><<<dim3(NROWS/8),dim3(128),0,stream>>>(ca,dOw,dOb,x,ln2_g,ln2_b,nullptr,x,nullptr);
  k_matvec<128,256,8,true><<<dim3(NROWS/8),dim3(256),0,stream>>>(x,nullptr,fw1,fb1,ffnh,NROWS);
  k_ffn2_ln3<<<dim3(NROWS/8),dim3(128),0,stream>>>(ffnh,fw2,fb2,x,ln3_g,ln3_b,counts,in_view,xf,out);
  k_head<<<dim3(NROWS),dim3(128),0,stream>>>(xf,in_qpos,pw1,pb1,pw2,pb2,out);
}

// Round 2
// 401.102 us; speedup vs baseline: 1.8866x; 1.8866x over previous
//
#include <hip/hip_runtime.h>
#include <hip/hip_bf16.h>
#include <math.h>

#define DEV __device__ __forceinline__

#define BB 2
#define VV 6
#define CC 128
#define NQ 1200
#define HH 8
#define PTSN 4
#define FFND 256
#define LVLSN 4
#define LTOT 29750
#define NROWS (BB*NQ)

__constant__ int c_W[4] = {200,100,50,25};
__constant__ int c_H[4] = {112,56,28,14};
__constant__ int c_S[4] = {0,22400,28000,29400};

DEV float bflo(unsigned u){ union{unsigned i; float f;}x; x.i = u<<16; return x.f; }
DEV float bfhi(unsigned u){ union{unsigned i; float f;}x; x.i = u&0xffff0000u; return x.f; }
DEV unsigned short f2bf(float f){ union{float f; unsigned i;}x; x.f=f; unsigned i=x.i;
  return (unsigned short)((i + 0x7fffu + ((i>>16)&1u))>>16); }
DEV unsigned addbf2(unsigned a, unsigned b){
  float lo = bflo(a)+bflo(b); float hi = bfhi(a)+bfhi(b);
  return (unsigned)f2bf(lo) | ((unsigned)f2bf(hi)<<16);
}
DEV float sigm(float z){ return 1.f/(1.f+__expf(-z)); }

typedef __attribute__((ext_vector_type(8))) short bf16x8;
typedef __attribute__((ext_vector_type(4))) float f32x4;

// ---------------- counts ----------------
__global__ void k_counts(const int* __restrict__ view, int* __restrict__ counts){
  int b = blockIdx.x;
  __shared__ int c[VV];
  if(threadIdx.x < VV) c[threadIdx.x]=0;
  __syncthreads();
  for(int n=threadIdx.x;n<NQ;n+=blockDim.x) atomicAdd(&c[view[b*NQ+n]],1);
  __syncthreads();
  if(threadIdx.x < VV) counts[b*VV+threadIdx.x]=c[threadIdx.x];
}

// ---------------- x transpose + qpe MLP ----------------
__global__ void k_prep(const float* __restrict__ iqf, const float* __restrict__ pos,
                       const float* __restrict__ w1, const float* __restrict__ b1,
                       const float* __restrict__ w2, const float* __restrict__ b2,
                       float* __restrict__ x, float* __restrict__ qpe){
  int row = blockIdx.x; int b = row/NQ, n = row%NQ;
  int t = threadIdx.x;
  __shared__ float hid[128];
  float p0 = pos[row*2+0], p1 = pos[row*2+1];
  hid[t] = fmaxf(p0*w1[t] + p1*w1[128+t] + b1[t], 0.f);
  x[(size_t)row*128 + t] = iqf[(size_t)b*CC*NQ + (size_t)t*NQ + n];
  __syncthreads();
  float acc = b2[t];
  #pragma unroll 4
  for(int c=0;c<128;c++) acc += hid[c]*w2[c*128 + t];
  qpe[(size_t)row*128+t] = acc;
}

// ---------------- kpe MLP + @d_val_w + bias -> kvpe (bf16) ----------------
__global__ void k_kvpe(const float* __restrict__ kpos,
                       const float* __restrict__ cw1, const float* __restrict__ cb1,
                       const float* __restrict__ cw2, const float* __restrict__ cb2,
                       const float* __restrict__ vw, const float* __restrict__ vb,
                       unsigned short* __restrict__ kvpe){
  int r0 = blockIdx.x*16; int t = threadIdx.x;
  __shared__ float hid[16][128];
  __shared__ float kpe[16][128];
  int d = t&127;
  for(int r = (t>>7); r<16; r+=2){
    int row = r0 + r; float p0=0.f,p1=0.f;
    if(row < LTOT){ p0 = kpos[row*2]; p1 = kpos[row*2+1]; }
    hid[r][d] = fmaxf(p0*cw1[d] + p1*cw1[128+d] + cb1[d], 0.f);
  }
  __syncthreads();
  int rb = (t>>7)*8;
  float acc[8];
  #pragma unroll
  for(int i=0;i<8;i++) acc[i] = cb2[d];
  #pragma unroll 4
  for(int c=0;c<128;c++){ float wv = cw2[c*128+d];
    #pragma unroll
    for(int i=0;i<8;i++) acc[i] += hid[rb+i][c]*wv; }
  #pragma unroll
  for(int i=0;i<8;i++) kpe[rb+i][d] = acc[i];
  __syncthreads();
  #pragma unroll
  for(int i=0;i<8;i++) acc[i] = vb[d];
  #pragma unroll 4
  for(int c=0;c<128;c++){ float wv = vw[c*128+d];
    #pragma unroll
    for(int i=0;i<8;i++) acc[i] += kpe[rb+i][c]*wv; }
  #pragma unroll
  for(int i=0;i<8;i++){ int row = r0+rb+i; if(row<LTOT) kvpe[(size_t)row*128+d] = f2bf(acc[i]); }
}

// ---------------- value projection GEMM (MFMA bf16) ----------------
// value[b,v,l,d] = sum_c feat[b,v,c,l] * W[c,d]  (+ kvpe[l,d] at epilogue)
// per block: 128 l x 128 d tile, K=128 in 4 chunks of 32. 4 waves, 64x64 quadrant each.
__global__ void __launch_bounds__(256) k_value_mfma(
    const float* __restrict__ f0, const float* __restrict__ f1,
    const float* __restrict__ f2, const float* __restrict__ f3,
    const unsigned short* __restrict__ kvpe, const float* __restrict__ vw,
    unsigned short* __restrict__ value){
  __shared__ unsigned short w_t[128][136]; // W^T [d][c], padded; 34816 B (reused as C staging)
  __shared__ unsigned short a_t[128][40];  // feat^T chunk [l][c0..c0+31], padded; 10240 B
  int t = threadIdx.x;
  int bv = blockIdx.y;
  int bx = blockIdx.x;
  int lvl, tile;
  if(bx < 175){ lvl=0; tile=bx; }
  else if(bx < 219){ lvl=1; tile=bx-175; }
  else if(bx < 230){ lvl=2; tile=bx-219; }
  else { lvl=3; tile=bx-230; }
  const int HW = (lvl==0)?22400:(lvl==1)?5600:(lvl==2)?1400:350;
  const int startL = (lvl==0)?0:(lvl==1)?22400:(lvl==2)?28000:29400;
  const float* feat = (lvl==0)?f0:(lvl==1)?f1:(lvl==2)?f2:f3;
  const float* fbase = feat + (size_t)bv*128*(size_t)HW;
  int l0 = tile*128;

  // stage W^T once: read W[c][d] coalesced (pairs of c rows), write [d][c] packed u32
  for(int i=t;i<8192;i+=256){
    int c = (i>>7)*2, d = i&127;
    unsigned pk = (unsigned)f2bf(vw[c*128+d]) | ((unsigned)f2bf(vw[(c+1)*128+d])<<16);
    *reinterpret_cast<unsigned*>(&w_t[d][c]) = pk;
  }

  int lane = t&63, wave = t>>6;
  int wl = wave>>1, wd = wave&1;     // quadrant: rows wl*64.., cols wd*64..
  int fr = lane&15, kg = lane>>4;    // fragment row/col, k-group

  f32x4 acc[4][4];
  #pragma unroll
  for(int i=0;i<4;i++)
    #pragma unroll
    for(int j=0;j<4;j++) acc[i][j] = (f32x4)0.f;

  for(int ck=0; ck<4; ck++){
    int c0 = ck*32;
    // gather A chunk into regs (transpose): unit = (oct, l); 8 strided-coalesced f32 rows
    unsigned pk[2][4];
    #pragma unroll
    for(int u=0;u<2;u++){
      int unit = t + u*256;
      int l = unit & 127, oct = unit >> 7;
      int gl = l0 + l;
      const float* fcol = fbase + (size_t)(c0 + oct*8)*HW + gl;
      unsigned short p8[8];
      #pragma unroll
      for(int j=0;j<8;j++){
        float v = (gl < HW) ? fcol[(size_t)j*HW] : 0.f;
        p8[j] = f2bf(v);
      }
      #pragma unroll
      for(int j=0;j<4;j++) pk[u][j] = (unsigned)p8[2*j] | ((unsigned)p8[2*j+1]<<16);
    }
    __syncthreads();   // prev chunk's ds_reads done (and W staging on ck=0)
    #pragma unroll
    for(int u=0;u<2;u++){
      int unit = t + u*256;
      int l = unit & 127, oct = unit >> 7;
      uint4 w4; w4.x=pk[u][0]; w4.y=pk[u][1]; w4.z=pk[u][2]; w4.w=pk[u][3];
      *reinterpret_cast<uint4*>(&a_t[l][oct*8]) = w4;
    }
    __syncthreads();
    bf16x8 af[4], bfr[4];
    #pragma unroll
    for(int i=0;i<4;i++) af[i] = *reinterpret_cast<const bf16x8*>(&a_t[wl*64 + i*16 + fr][kg*8]);
    #pragma unroll
    for(int j=0;j<4;j++) bfr[j] = *reinterpret_cast<const bf16x8*>(&w_t[wd*64 + j*16 + fr][c0 + kg*8]);
    #pragma unroll
    for(int i=0;i<4;i++)
      #pragma unroll
      for(int j=0;j<4;j++)
        acc[i][j] = __builtin_amdgcn_mfma_f32_16x16x32_bf16(af[i], bfr[j], acc[i][j], 0, 0, 0);
  }

  // epilogue: restage C through LDS (reuse w_t), coalesced global writes + kvpe add
  __syncthreads();
  unsigned short (*c_l)[136] = w_t;
  #pragma unroll
  for(int i=0;i<4;i++){
    int lbase = wl*64 + i*16 + kg*4;
    #pragma unroll
    for(int j=0;j<4;j++){
      int d = wd*64 + j*16 + fr;
      #pragma unroll
      for(int r=0;r<4;r++) c_l[lbase + r][d] = f2bf(acc[i][j][r]);
    }
  }
  __syncthreads();
  for(int i=t;i<128*16;i+=256){
    int row = i>>4, seg = i&15;
    int gl = l0 + row;
    if(gl >= HW) continue;
    uint4 cu = *reinterpret_cast<const uint4*>(&c_l[row][seg*8]);
    const uint4 ku = *reinterpret_cast<const uint4*>(kvpe + (size_t)(startL+gl)*CC + seg*8);
    uint4 ou;
    ou.x = addbf2(cu.x, ku.x); ou.y = addbf2(cu.y, ku.y);
    ou.z = addbf2(cu.z, ku.z); ou.w = addbf2(cu.w, ku.w);
    *reinterpret_cast<uint4*>(value + ((size_t)bv*LTOT + startL + gl)*CC + seg*8) = ou;
  }
}

// ---------------- generic R-row batched matvec ----------------
template<int K, int N, int R, bool RELU>
__global__ void k_matvec(const float* __restrict__ in, const float* __restrict__ in2,
                         const float* __restrict__ W, const float* __restrict__ bias,
                         float* __restrict__ out, int nrows){
  int r0 = blockIdx.x*R; int d = threadIdx.x;
  __shared__ float s_in[R][K];
  for(int i=d;i<R*K;i+=N){
    int r=i/K, c=i%K; int row=r0+r;
    float v=0.f;
    if(row<nrows){ v = in[(size_t)row*K+c]; if(in2) v += in2[(size_t)row*K+c]; }
    s_in[r][c]=v;
  }
  __syncthreads();
  float acc[R];
  #pragma unroll
  for(int r=0;r<R;r++) acc[r]=bias[d];
  #pragma unroll 4
  for(int c=0;c<K;c++){ float wv = W[(size_t)c*N+d];
    #pragma unroll
    for(int r=0;r<R;r++) acc[r] += s_in[r][c]*wv; }
  #pragma unroll
  for(int r=0;r<R;r++){
    int row=r0+r;
    if(row<nrows){ float v=acc[r]; if(RELU) v=fmaxf(v,0.f); out[(size_t)row*N+d]=v; }
  }
}

// ---------------- masked self-attention (online softmax) ----------------
#define QT 64
#define KT 256
__global__ void k_attn(const float* __restrict__ qkv, const int* __restrict__ view,
                       float* __restrict__ att){
  int qt = blockIdx.x, h = blockIdx.y, b = blockIdx.z;
  int n0 = qt*QT;
  int t = threadIdx.x;
  __shared__ float q_s[QT][17];
  __shared__ float k_s[KT][16];
  __shared__ float v_s[KT][16];
  __shared__ int qv_s[QT];
  __shared__ int kv_s[KT];
  __shared__ float red[4][QT][18];
  for(int i=t;i<QT*16;i+=256){ int r=i>>4,c=i&15; int n=n0+r;
    q_s[r][c] = (n<NQ)? qkv[((size_t)b*NQ+n)*384 + h*16 + c] : 0.f; }
  for(int i=t;i<QT;i+=256){ int n=n0+i; qv_s[i] = (n<NQ)? view[b*NQ+n] : -1; }
  __syncthreads();
  int qi = t&63, sub = t>>6;
  int myview = qv_s[qi];
  float m = -1e30f, s = 0.f, acc[16];
  #pragma unroll
  for(int c=0;c<16;c++) acc[c]=0.f;
  for(int m0=0; m0<NQ; m0+=KT){
    __syncthreads();
    int kn = NQ-m0; if(kn>KT) kn=KT;
    for(int i=t;i<KT*16;i+=256){ int r=i>>4,c=i&15;
      float kv=0.f, vv=0.f;
      if(r<kn){ size_t base=((size_t)b*NQ+m0+r)*384 + h*16 + c;
        kv = qkv[base+128]; vv = qkv[base+256]; }
      k_s[r][c]=kv; v_s[r][c]=vv; }
    for(int i=t;i<KT;i+=256){ kv_s[i] = (i<kn)? view[b*NQ+m0+i] : -12345; }
    __syncthreads();
    for(int mm=sub; mm<kn; mm+=4){
      if(kv_s[mm]!=myview) continue;
      float l=0.f;
      #pragma unroll
      for(int c=0;c<16;c++) l += q_s[qi][c]*k_s[mm][c];
      l *= 0.25f;
      float newm = fmaxf(m,l);
      float e = __expf(l - newm);
      if(newm > m){
        float rr = __expf(m - newm);
        s *= rr;
        #pragma unroll
        for(int c=0;c<16;c++) acc[c]*=rr;
        m = newm;
      }
      s += e;
      #pragma unroll
      for(int c=0;c<16;c++) acc[c] += e*v_s[mm][c];
    }
  }
  red[sub][qi][0]=m; red[sub][qi][1]=s;
  #pragma unroll
  for(int c=0;c<16;c++) red[sub][qi][2+c]=acc[c];
  __syncthreads();
  if(sub==0){
    float M=-1e30f;
    #pragma unroll
    for(int j=0;j<4;j++) M=fmaxf(M,red[j][qi][0]);
    float S=0.f; float o[16];
    #pragma unroll
    for(int c=0;c<16;c++) o[c]=0.f;
    #pragma unroll
    for(int j=0;j<4;j++){ float e=__expf(red[j][qi][0]-M); S += e*red[j][qi][1];
      #pragma unroll
      for(int c=0;c<16;c++) o[c] += e*red[j][qi][2+c]; }
    int n=n0+qi;
    if(n<NQ){ float inv = 1.f/S;
      #pragma unroll
      for(int c=0;c<16;c++) att[((size_t)b*NQ+n)*128 + h*16 + c] = o[c]*inv; }
  }
}

// ---------------- proj + residual + LN (optional qc=ln_out+qpe) ----------------
template<bool WQC>
__global__ void k_proj_ln(const float* __restrict__ in, const float* __restrict__ W,
                          const float* __restrict__ bias, const float* __restrict__ resid,
                          const float* __restrict__ g, const float* __restrict__ bb,
                          const float* __restrict__ qpe, float* __restrict__ xout,
                          float* __restrict__ qc){
  int r0 = blockIdx.x*8; int d = threadIdx.x;
  __shared__ float s_in[8][128];
  __shared__ float s_m[8][2][2];
  for(int i=d;i<8*128;i+=128){ int r=i>>7, c=i&127; s_in[r][c] = in[(size_t)(r0+r)*128 + c]; }
  __syncthreads();
  float acc[8];
  #pragma unroll
  for(int r=0;r<8;r++) acc[r]=bias[d];
  #pragma unroll 4
  for(int c=0;c<128;c++){ float wv = W[c*128+d];
    #pragma unroll
    for(int r=0;r<8;r++) acc[r] += s_in[r][c]*wv; }
  float v[8];
  int lane = d&63, wid = d>>6;
  #pragma unroll
  for(int r=0;r<8;r++){
    v[r] = acc[r] + resid[(size_t)(r0+r)*128 + d];
    float s1=v[r], s2=v[r]*v[r];
    for(int o=32;o>0;o>>=1){ s1 += __shfl_down(s1,o); s2 += __shfl_down(s2,o); }
    if(lane==0){ s_m[r][wid][0]=s1; s_m[r][wid][1]=s2; }
  }
  __syncthreads();
  #pragma unroll
  for(int r=0;r<8;r++){
    float S1=s_m[r][0][0]+s_m[r][1][0], S2=s_m[r][0][1]+s_m[r][1][1];
    float mean=S1*(1.f/128.f), var=S2*(1.f/128.f)-mean*mean;
    float rs=rsqrtf(var+1e-5f);
    float o=(v[r]-mean)*rs*g[d]+bb[d];
    xout[(size_t)(r0+r)*128+d]=o;
    if(WQC) qc[(size_t)(r0+r)*128+d]=o+qpe[(size_t)(r0+r)*128+d];
  }
}

// ---------------- attn-weight matvec + per-head softmax(16) ----------------
__global__ void k_aw(const float* __restrict__ qc, const float* __restrict__ W,
                     const float* __restrict__ bias, float* __restrict__ aw){
  int r0 = blockIdx.x*8; int d = threadIdx.x;
  __shared__ float s_in[8][128];
  __shared__ float s_out[8][130];
  for(int i=d;i<8*128;i+=128){ int r=i>>7, c=i&127; s_in[r][c]=qc[(size_t)(r0+r)*128+c]; }
  __syncthreads();
  float acc[8];
  #pragma unroll
  for(int r=0;r<8;r++) acc[r]=bias[d];
  #pragma unroll 4
  for(int c=0;c<128;c++){ float wv = W[c*128+d];
    #pragma unroll
    for(int r=0;r<8;r++) acc[r] += s_in[r][c]*wv; }
  #pragma unroll
  for(int r=0;r<8;r++) s_out[r][d]=acc[r];
  __syncthreads();
  if(d < 64){
    int r = d>>3, h = d&7;
    float mx=-1e30f;
    #pragma unroll
    for(int i=0;i<16;i++) mx = fmaxf(mx, s_out[r][h*16+i]);
    float e[16]; float sm=0.f;
    #pragma unroll
    for(int i=0;i<16;i++){ e[i]=__expf(s_out[r][h*16+i]-mx); sm+=e[i]; }
    float inv = 1.f/sm;
    #pragma unroll
    for(int i=0;i<16;i++) aw[(size_t)(r0+r)*128 + h*16+i] = e[i]*inv;
  }
}

// ---------------- deformable bilinear sampling ----------------
__global__ void k_sample(const float* __restrict__ qpos, const int* __restrict__ view,
                         const float* __restrict__ offb, const float* __restrict__ awb,
                         const unsigned short* __restrict__ value, float* __restrict__ ca){
  int n = blockIdx.x, b = blockIdx.y;
  size_t row = (size_t)b*NQ + n;
  int t = threadIdx.x;
  int h = t>>4, lp = t&15, lvl = lp>>2;
  float rx = sigm(qpos[row*2]), ry = sigm(qpos[row*2+1]);
  int vw = view[row];
  int w = c_W[lvl], hh = c_H[lvl];
  float ox = offb[row*256 + t*2], oy = offb[row*256 + t*2+1];
  float a = awb[row*128 + t];
  float lx = rx*(float)w + ox - 0.5f;
  float ly = ry*(float)hh + oy - 0.5f;
  float x0f = floorf(lx), y0f = floorf(ly);
  float fx = lx - x0f, fy = ly - y0f;
  int x0 = (int)x0f, y0 = (int)y0f;
  float samp[16];
  #pragma unroll
  for(int c=0;c<16;c++) samp[c]=0.f;
  size_t brow = ((size_t)(b*VV + vw))*LTOT + c_S[lvl];
  #pragma unroll
  for(int dy=0;dy<2;dy++){
    #pragma unroll
    for(int dx=0;dx<2;dx++){
      int xi=x0+dx, yi=y0+dy;
      if(xi<0||xi>=w||yi<0||yi>=hh) continue;
      float wt = (dx?fx:(1.f-fx))*(dy?fy:(1.f-fy));
      const uint4* vp = reinterpret_cast<const uint4*>(value + (brow + (size_t)yi*w + xi)*CC + h*16);
      uint4 u0 = vp[0], u1 = vp[1];
      samp[0] += wt*bflo(u0.x); samp[1] += wt*bfhi(u0.x);
      samp[2] += wt*bflo(u0.y); samp[3] += wt*bfhi(u0.y);
      samp[4] += wt*bflo(u0.z); samp[5] += wt*bfhi(u0.z);
      samp[6] += wt*bflo(u0.w); samp[7] += wt*bfhi(u0.w);
      samp[8] += wt*bflo(u1.x); samp[9] += wt*bfhi(u1.x);
      samp[10]+= wt*bflo(u1.y); samp[11]+= wt*bfhi(u1.y);
      samp[12]+= wt*bflo(u1.z); samp[13]+= wt*bfhi(u1.z);
      samp[14]+= wt*bflo(u1.w); samp[15]+= wt*bfhi(u1.w);
    }
  }
  __shared__ float sred[128][17];
  #pragma unroll
  for(int c=0;c<16;c++) sred[t][c] = a*samp[c];
  __syncthreads();
  int h2=t>>4, c2=t&15;
  float sum=0.f;
  #pragma unroll
  for(int j=0;j<16;j++) sum += sred[h2*16+j][c2];
  ca[row*128 + t] = sum;
}

// ---------------- FFN2 + LN3 + valid-zero + out0 transpose ----------------
__global__ void k_ffn2_ln3(const float* __restrict__ hin, const float* __restrict__ W,
                           const float* __restrict__ bias, const float* __restrict__ resid,
                           const float* __restrict__ g, const float* __restrict__ bb,
                           const int* __restrict__ counts, const int* __restrict__ view,
                           float* __restrict__ xf, float* __restrict__ out0){
  int r0 = blockIdx.x*8; int d = threadIdx.x;
  __shared__ float s_in[8][256];
  __shared__ float s_m[8][2][2];
  for(int i=d;i<8*256;i+=128){ int r=i>>8, c=i&255; s_in[r][c]=hin[(size_t)(r0+r)*256+c]; }
  __syncthreads();
  float acc[8];
  #pragma unroll
  for(int r=0;r<8;r++) acc[r]=bias[d];
  #pragma unroll 4
  for(int c=0;c<256;c++){ float wv = W[c*128+d];
    #pragma unroll
    for(int r=0;r<8;r++) acc[r] += s_in[r][c]*wv; }
  float v[8];
  int lane = d&63, wid = d>>6;
  #pragma unroll
  for(int r=0;r<8;r++){
    v[r] = acc[r] + resid[(size_t)(r0+r)*128 + d];
    float s1=v[r], s2=v[r]*v[r];
    for(int o=32;o>0;o>>=1){ s1 += __shfl_down(s1,o); s2 += __shfl_down(s2,o); }
    if(lane==0){ s_m[r][wid][0]=s1; s_m[r][wid][1]=s2; }
  }
  __syncthreads();
  #pragma unroll
  for(int r=0;r<8;r++){
    float S1=s_m[r][0][0]+s_m[r][1][0], S2=s_m[r][0][1]+s_m[r][1][1];
    float mean=S1*(1.f/128.f), var=S2*(1.f/128.f)-mean*mean;
    float rs=rsqrtf(var+1e-5f);
    float o=(v[r]-mean)*rs*g[d]+bb[d];
    int row=r0+r; int b=row/NQ, n=row%NQ;
    bool val = counts[b*VV + view[row]] > 1;
    float oz = val ? o : 0.f;
    xf[(size_t)row*128+d]=oz;
    out0[((size_t)b*CC + d)*NQ + n]=oz;
  }
}

// ---------------- prediction head ----------------
__global__ void k_head(const float* __restrict__ xf, const float* __restrict__ pos,
                       const float* __restrict__ w1, const float* __restrict__ b1,
                       const float* __restrict__ w2, const float* __restrict__ b2,
                       float* __restrict__ dout){
  int row = blockIdx.x; int b=row/NQ, n=row%NQ; int t=threadIdx.x;
  __shared__ float xs[128];
  __shared__ float hid[128];
  __shared__ float res[6];
  xs[t] = xf[(size_t)row*128+t];
  __syncthreads();
  float a = b1[t];
  #pragma unroll 4
  for(int c=0;c<128;c++) a += xs[c]*w1[c*128+t];
  hid[t]=fmaxf(a,0.f);
  __syncthreads();
  if(t<6){ float a2=b2[t];
    #pragma unroll 4
    for(int c=0;c<128;c++) a2 += hid[c]*w2[c*6+t];
    res[t]=a2; }
  __syncthreads();
  if(t==0){
    const int O1 = BB*CC*NQ;            // 307200
    const int O2 = O1 + BB*NQ*2;        // 312000
    const int O3 = O2 + BB*2*NQ;        // 316800
    const int O4 = O3 + BB*4*NQ;        // 326400
    float p0=pos[row*2], p1=pos[row*2+1];
    float cr0 = res[0]+p0, cr1 = res[1]+p1;
    dout[O1 + row*2]   = cr0;
    dout[O1 + row*2+1] = cr1;
    float cen0 = sigm(cr0), cen1 = sigm(cr1);
    dout[O2 + (b*2+0)*NQ + n] = cen0;
    dout[O2 + (b*2+1)*NQ + n] = cen1;
    float f0=sigm(res[2]), f1=sigm(res[3]), f2=sigm(res[4]), f3=sigm(res[5]);
    dout[O3 + (b*4+0)*NQ + n] = f0;
    dout[O3 + (b*4+1)*NQ + n] = f1;
    dout[O3 + (b*4+2)*NQ + n] = f2;
    dout[O3 + (b*4+3)*NQ + n] = f3;
    float bw=f0+f2, bh=f1+f3;
    float cx=(2.f*cen0 - f0 + f2)*0.5f;
    float cy=(2.f*cen1 - f1 + f3)*0.5f;
    dout[O4 + (b*4+0)*NQ + n] = cx;
    dout[O4 + (b*4+1)*NQ + n] = cy;
    dout[O4 + (b*4+2)*NQ + n] = bw;
    dout[O4 + (b*4+3)*NQ + n] = bh;
  }
}

extern "C" void kernel_launch(void* const* d_in, const int* in_sizes, int n_in,
                              void* d_out, int out_size, void* d_ws, size_t ws_size,
                              hipStream_t stream){
  (void)in_sizes; (void)n_in; (void)out_size; (void)ws_size;
  const float* in_iqf  = (const float*)d_in[0];
  const float* in_qpos = (const float*)d_in[1];
  const float* in_feat[4] = {(const float*)d_in[2],(const float*)d_in[3],(const float*)d_in[4],(const float*)d_in[5]};
  const float* in_kpos = (const float*)d_in[6];
  const float* sp_w1=(const float*)d_in[7], *sp_b1=(const float*)d_in[8], *sp_w2=(const float*)d_in[9], *sp_b2=(const float*)d_in[10];
  const float* cp_w1=(const float*)d_in[11], *cp_b1=(const float*)d_in[12], *cp_w2=(const float*)d_in[13], *cp_b2=(const float*)d_in[14];
  const float* sa_wqkv=(const float*)d_in[15], *sa_bqkv=(const float*)d_in[16], *sa_wo=(const float*)d_in[17], *sa_bo=(const float*)d_in[18];
  const float* ln1_g=(const float*)d_in[19], *ln1_b=(const float*)d_in[20];
  const float* dvw=(const float*)d_in[21], *dvb=(const float*)d_in[22];
  const float* dow=(const float*)d_in[23], *dob=(const float*)d_in[24];
  const float* daw=(const float*)d_in[25], *dab=(const float*)d_in[26];
  const float* dOw=(const float*)d_in[27], *dOb=(const float*)d_in[28];
  const float* ln2_g=(const float*)d_in[29], *ln2_b=(const float*)d_in[30];
  const float* fw1=(const float*)d_in[31], *fb1=(const float*)d_in[32], *fw2=(const float*)d_in[33], *fb2=(const float*)d_in[34];
  const float* ln3_g=(const float*)d_in[35], *ln3_b=(const float*)d_in[36];
  const float* pw1=(const float*)d_in[37], *pb1=(const float*)d_in[38], *pw2=(const float*)d_in[39], *pb2=(const float*)d_in[40];
  const int* in_view = (const int*)d_in[41];
  float* out = (float*)d_out;

  char* ws = (char*)d_ws;
  unsigned short* value = (unsigned short*)ws;                       // 91,392,000 B
  unsigned short* kvpe  = (unsigned short*)(ws + 91392000);          //  7,616,000 B
  float* f = (float*)(ws + 91392000 + 7616000);
  float* qpe  = f;               // 307200
  float* x    = f + 307200;      // 307200
  float* qkv  = f + 614400;      // 921600
  float* att  = f + 1536000;     // 307200
  float* qc   = f + 1843200;     // 307200
  float* offb = f + 2150400;     // 614400
  float* awb  = f + 2764800;     // 307200
  float* ca   = f + 3072000;     // 307200
  float* ffnh = f + 3379200;     // 614400
  float* xf   = f + 3993600;     // 307200
  int* counts = (int*)(f + 4300800);

  k_counts<<<dim3(BB),dim3(256),0,stream>>>(in_view, counts);
  k_prep<<<dim3(NROWS),dim3(128),0,stream>>>(in_iqf,in_qpos,sp_w1,sp_b1,sp_w2,sp_b2,x,qpe);
  k_kvpe<<<dim3((LTOT+15)/16),dim3(256),0,stream>>>(in_kpos,cp_w1,cp_b1,cp_w2,cp_b2,dvw,dvb,kvpe);
  k_value_mfma<<<dim3(233, BB*VV),dim3(256),0,stream>>>(in_feat[0],in_feat[1],in_feat[2],in_feat[3],kvpe,dvw,value);
  k_matvec<128,384,8,false><<<dim3(NROWS/8),dim3(384),0,stream>>>(x,qpe,sa_wqkv,sa_bqkv,qkv,NROWS);
  k_attn<<<dim3((NQ+QT-1)/QT,HH,BB),dim3(256),0,stream>>>(qkv,in_view,att);
  k_proj_ln<true><<<dim3(NROWS/8),dim3(128),0,stream>>>(att,sa_wo,sa_bo,x,ln1_g,ln1_b,qpe,x,qc);
  k_matvec<128,256,8,false><<<dim3(NROWS/8),dim3(256),0,stream>>>(qc,nullptr,dow,dob,offb,NROWS);
  k_aw<<<dim3(NROWS/8),dim3(128),0,stream>>>(qc,daw,dab,awb);
  k_sample<<<dim3(NQ,BB),dim3(128),0,stream>>>(in_qpos,in_view,offb,awb,value,ca);
  k_proj_ln<false><<<dim3(NROWS/8),dim3(128),0,stream>>>(ca,dOw,dOb,x,ln2_g,ln2_b,nullptr,x,nullptr);
  k_matvec<128,256,8,true><<<dim3(NROWS/8),dim3(256),0,stream>>>(x,nullptr,fw1,fb1,ffnh,NROWS);
  k_ffn2_ln3<<<dim3(NROWS/8),dim3(128),0,stream>>>(ffnh,fw2,fb2,x,ln3_g,ln3_b,counts,in_view,xf,out);
  k_head<<<dim3(NROWS),dim3(128),0,stream>>>(xf,in_qpos,pw1,pb1,pw2,pb2,out);
}

// Round 3
// 306.919 us; speedup vs baseline: 2.4655x; 1.3069x over previous
//
#include <hip/hip_runtime.h>
#include <hip/hip_bf16.h>
#include <math.h>

#define DEV __device__ __forceinline__

#define BB 2
#define VV 6
#define CC 128
#define NQ 1200
#define HH 8
#define PTSN 4
#define FFND 256
#define LVLSN 4
#define LTOT 29750
#define NROWS (BB*NQ)

__constant__ int c_W[4] = {200,100,50,25};
__constant__ int c_H[4] = {112,56,28,14};
__constant__ int c_S[4] = {0,22400,28000,29400};

DEV float bflo(unsigned u){ union{unsigned i; float f;}x; x.i = u<<16; return x.f; }
DEV float bfhi(unsigned u){ union{unsigned i; float f;}x; x.i = u&0xffff0000u; return x.f; }
DEV unsigned short f2bf(float f){ union{float f; unsigned i;}x; x.f=f; unsigned i=x.i;
  return (unsigned short)((i + 0x7fffu + ((i>>16)&1u))>>16); }
DEV unsigned addbf2(unsigned a, unsigned b){
  float lo = bflo(a)+bflo(b); float hi = bfhi(a)+bfhi(b);
  return (unsigned)f2bf(lo) | ((unsigned)f2bf(hi)<<16);
}
DEV float sigm(float z){ return 1.f/(1.f+__expf(-z)); }

typedef __attribute__((ext_vector_type(8))) short bf16x8;
typedef __attribute__((ext_vector_type(4))) float f32x4;

// ---------------- bucket queries by (b, view): deterministic rank via ballot ----------------
// order[(b*VV+v)*NQ + rank] = n (ascending n), counts[b*VV+v]
__global__ void k_bucket(const int* __restrict__ view, int* __restrict__ order,
                         int* __restrict__ counts){
  int b = blockIdx.x; int lane = threadIdx.x; // 64 threads
  int base0=0,base1=0,base2=0,base3=0,base4=0,base5=0;
  for(int c0=0;c0<NQ;c0+=64){
    int n = c0 + lane;
    int v = (n<NQ) ? view[b*NQ+n] : -1;
    unsigned long long lower = (lane==63)? 0x7fffffffffffffffull : ((1ull<<lane)-1ull);
    #define BUCKET_STEP(VVV, BASE) { \
      unsigned long long mk = __ballot(v==VVV); \
      if(v==VVV){ int r = BASE + __popcll(mk & lower); order[(b*VV+VVV)*NQ + r] = n; } \
      BASE += __popcll(mk); }
    BUCKET_STEP(0, base0) BUCKET_STEP(1, base1) BUCKET_STEP(2, base2)
    BUCKET_STEP(3, base3) BUCKET_STEP(4, base4) BUCKET_STEP(5, base5)
    #undef BUCKET_STEP
  }
  if(lane==0){
    counts[b*VV+0]=base0; counts[b*VV+1]=base1; counts[b*VV+2]=base2;
    counts[b*VV+3]=base3; counts[b*VV+4]=base4; counts[b*VV+5]=base5;
  }
}

// ---------------- x transpose + qpe MLP ----------------
__global__ void k_prep(const float* __restrict__ iqf, const float* __restrict__ pos,
                       const float* __restrict__ w1, const float* __restrict__ b1,
                       const float* __restrict__ w2, const float* __restrict__ b2,
                       float* __restrict__ x, float* __restrict__ qpe){
  int row = blockIdx.x; int b = row/NQ, n = row%NQ;
  int t = threadIdx.x;
  __shared__ float hid[128];
  float p0 = pos[row*2+0], p1 = pos[row*2+1];
  hid[t] = fmaxf(p0*w1[t] + p1*w1[128+t] + b1[t], 0.f);
  x[(size_t)row*128 + t] = iqf[(size_t)b*CC*NQ + (size_t)t*NQ + n];
  __syncthreads();
  float acc = b2[t];
  #pragma unroll 4
  for(int c=0;c<128;c++) acc += hid[c]*w2[c*128 + t];
  qpe[(size_t)row*128+t] = acc;
}

// ---------------- kpe MLP + @d_val_w + bias -> kvpe (bf16) ----------------
__global__ void k_kvpe(const float* __restrict__ kpos,
                       const float* __restrict__ cw1, const float* __restrict__ cb1,
                       const float* __restrict__ cw2, const float* __restrict__ cb2,
                       const float* __restrict__ vw, const float* __restrict__ vb,
                       unsigned short* __restrict__ kvpe){
  int r0 = blockIdx.x*16; int t = threadIdx.x;
  __shared__ float hid[16][128];
  __shared__ float kpe[16][128];
  int d = t&127;
  for(int r = (t>>7); r<16; r+=2){
    int row = r0 + r; float p0=0.f,p1=0.f;
    if(row < LTOT){ p0 = kpos[row*2]; p1 = kpos[row*2+1]; }
    hid[r][d] = fmaxf(p0*cw1[d] + p1*cw1[128+d] + cb1[d], 0.f);
  }
  __syncthreads();
  int rb = (t>>7)*8;
  float acc[8];
  #pragma unroll
  for(int i=0;i<8;i++) acc[i] = cb2[d];
  #pragma unroll 4
  for(int c=0;c<128;c++){ float wv = cw2[c*128+d];
    #pragma unroll
    for(int i=0;i<8;i++) acc[i] += hid[rb+i][c]*wv; }
  #pragma unroll
  for(int i=0;i<8;i++) kpe[rb+i][d] = acc[i];
  __syncthreads();
  #pragma unroll
  for(int i=0;i<8;i++) acc[i] = vb[d];
  #pragma unroll 4
  for(int c=0;c<128;c++){ float wv = vw[c*128+d];
    #pragma unroll
    for(int i=0;i<8;i++) acc[i] += kpe[rb+i][c]*wv; }
  #pragma unroll
  for(int i=0;i<8;i++){ int row = r0+rb+i; if(row<LTOT) kvpe[(size_t)row*128+d] = f2bf(acc[i]); }
}

// ---------------- value projection GEMM (MFMA bf16) ----------------
__global__ void __launch_bounds__(256) k_value_mfma(
    const float* __restrict__ f0, const float* __restrict__ f1,
    const float* __restrict__ f2, const float* __restrict__ f3,
    const unsigned short* __restrict__ kvpe, const float* __restrict__ vw,
    unsigned short* __restrict__ value){
  __shared__ unsigned short w_t[128][136]; // W^T [d][c], padded (reused as C staging)
  __shared__ unsigned short a_t[128][40];  // feat^T chunk [l][c0..c0+31], padded
  int t = threadIdx.x;
  int bv = blockIdx.y;
  int bx = blockIdx.x;
  int lvl, tile;
  if(bx < 175){ lvl=0; tile=bx; }
  else if(bx < 219){ lvl=1; tile=bx-175; }
  else if(bx < 230){ lvl=2; tile=bx-219; }
  else { lvl=3; tile=bx-230; }
  const int HW = (lvl==0)?22400:(lvl==1)?5600:(lvl==2)?1400:350;
  const int startL = (lvl==0)?0:(lvl==1)?22400:(lvl==2)?28000:29400;
  const float* feat = (lvl==0)?f0:(lvl==1)?f1:(lvl==2)?f2:f3;
  const float* fbase = feat + (size_t)bv*128*(size_t)HW;
  int l0 = tile*128;

  for(int i=t;i<8192;i+=256){
    int c = (i>>7)*2, d = i&127;
    unsigned pk = (unsigned)f2bf(vw[c*128+d]) | ((unsigned)f2bf(vw[(c+1)*128+d])<<16);
    *reinterpret_cast<unsigned*>(&w_t[d][c]) = pk;
  }

  int lane = t&63, wave = t>>6;
  int wl = wave>>1, wd = wave&1;
  int fr = lane&15, kg = lane>>4;

  f32x4 acc[4][4];
  #pragma unroll
  for(int i=0;i<4;i++)
    #pragma unroll
    for(int j=0;j<4;j++) acc[i][j] = (f32x4)0.f;

  for(int ck=0; ck<4; ck++){
    int c0 = ck*32;
    unsigned pk[2][4];
    #pragma unroll
    for(int u=0;u<2;u++){
      int unit = t + u*256;
      int l = unit & 127, oct = unit >> 7;
      int gl = l0 + l;
      const float* fcol = fbase + (size_t)(c0 + oct*8)*HW + gl;
      unsigned short p8[8];
      #pragma unroll
      for(int j=0;j<8;j++){
        float v = (gl < HW) ? fcol[(size_t)j*HW] : 0.f;
        p8[j] = f2bf(v);
      }
      #pragma unroll
      for(int j=0;j<4;j++) pk[u][j] = (unsigned)p8[2*j] | ((unsigned)p8[2*j+1]<<16);
    }
    __syncthreads();
    #pragma unroll
    for(int u=0;u<2;u++){
      int unit = t + u*256;
      int l = unit & 127, oct = unit >> 7;
      uint4 w4; w4.x=pk[u][0]; w4.y=pk[u][1]; w4.z=pk[u][2]; w4.w=pk[u][3];
      *reinterpret_cast<uint4*>(&a_t[l][oct*8]) = w4;
    }
    __syncthreads();
    bf16x8 af[4], bfr[4];
    #pragma unroll
    for(int i=0;i<4;i++) af[i] = *reinterpret_cast<const bf16x8*>(&a_t[wl*64 + i*16 + fr][kg*8]);
    #pragma unroll
    for(int j=0;j<4;j++) bfr[j] = *reinterpret_cast<const bf16x8*>(&w_t[wd*64 + j*16 + fr][c0 + kg*8]);
    #pragma unroll
    for(int i=0;i<4;i++)
      #pragma unroll
      for(int j=0;j<4;j++)
        acc[i][j] = __builtin_amdgcn_mfma_f32_16x16x32_bf16(af[i], bfr[j], acc[i][j], 0, 0, 0);
  }

  __syncthreads();
  unsigned short (*c_l)[136] = w_t;
  #pragma unroll
  for(int i=0;i<4;i++){
    int lbase = wl*64 + i*16 + kg*4;
    #pragma unroll
    for(int j=0;j<4;j++){
      int d = wd*64 + j*16 + fr;
      #pragma unroll
      for(int r=0;r<4;r++) c_l[lbase + r][d] = f2bf(acc[i][j][r]);
    }
  }
  __syncthreads();
  for(int i=t;i<128*16;i+=256){
    int row = i>>4, seg = i&15;
    int gl = l0 + row;
    if(gl >= HW) continue;
    uint4 cu = *reinterpret_cast<const uint4*>(&c_l[row][seg*8]);
    const uint4 ku = *reinterpret_cast<const uint4*>(kvpe + (size_t)(startL+gl)*CC + seg*8);
    uint4 ou;
    ou.x = addbf2(cu.x, ku.x); ou.y = addbf2(cu.y, ku.y);
    ou.z = addbf2(cu.z, ku.z); ou.w = addbf2(cu.w, ku.w);
    *reinterpret_cast<uint4*>(value + ((size_t)bv*LTOT + startL + gl)*CC + seg*8) = ou;
  }
}

// ---------------- generic R-row batched matvec ----------------
template<int K, int N, int R, bool RELU>
__global__ void k_matvec(const float* __restrict__ in, const float* __restrict__ in2,
                         const float* __restrict__ W, const float* __restrict__ bias,
                         float* __restrict__ out, int nrows){
  int r0 = blockIdx.x*R; int d = threadIdx.x;
  __shared__ float s_in[R][K];
  for(int i=d;i<R*K;i+=N){
    int r=i/K, c=i%K; int row=r0+r;
    float v=0.f;
    if(row<nrows){ v = in[(size_t)row*K+c]; if(in2) v += in2[(size_t)row*K+c]; }
    s_in[r][c]=v;
  }
  __syncthreads();
  float acc[R];
  #pragma unroll
  for(int r=0;r<R;r++) acc[r]=bias[d];
  #pragma unroll 4
  for(int c=0;c<K;c++){ float wv = W[(size_t)c*N+d];
    #pragma unroll
    for(int r=0;r<R;r++) acc[r] += s_in[r][c]*wv; }
  #pragma unroll
  for(int r=0;r<R;r++){
    int row=r0+r;
    if(row<nrows){ float v=acc[r]; if(RELU) v=fmaxf(v,0.f); out[(size_t)row*N+d]=v; }
  }
}

// ---------------- bucketed self-attention (per-view, no mask, no divergence) ----------------
#define QT2 64
#define KT2 128
__global__ void __launch_bounds__(256) k_attn_v(const float* __restrict__ qkv,
        const int* __restrict__ order, const int* __restrict__ counts,
        float* __restrict__ att){
  int qt = blockIdx.x;
  int vh = blockIdx.y; int v = vh>>3, h = vh&7;
  int b = blockIdx.z;
  int C = counts[b*VV+v];
  int q0 = qt*QT2;
  if(q0 >= C) return;
  const int* ord = order + (size_t)(b*VV+v)*NQ;
  int t = threadIdx.x;
  __shared__ float q_s[QT2][17];
  __shared__ int qn_s[QT2];
  __shared__ float k_s[KT2][16];
  __shared__ float v_s[KT2][16];
  __shared__ float red[4][QT2][18];
  for(int i=t;i<QT2;i+=256){ int qi=q0+i; qn_s[i] = (qi<C)? ord[qi] : -1; }
  __syncthreads();
  for(int i=t;i<QT2*16;i+=256){ int r=i>>4,c=i&15; int n=qn_s[r];
    q_s[r][c] = (n>=0)? qkv[((size_t)b*NQ+n)*384 + h*16 + c] : 0.f; }
  int qi = t&63, sub = t>>6;
  float m = -1e30f, s = 0.f, acc[16];
  #pragma unroll
  for(int c=0;c<16;c++) acc[c]=0.f;
  for(int k0=0; k0<C; k0+=KT2){
    int kn = C-k0; if(kn>KT2) kn=KT2;
    __syncthreads();
    for(int i=t;i<KT2*16;i+=256){ int r=i>>4,c=i&15;
      float kv=0.f, vv=0.f;
      if(r<kn){ int n=ord[k0+r]; size_t base=((size_t)b*NQ+n)*384 + h*16 + c;
        kv = qkv[base+128]; vv = qkv[base+256]; }
      k_s[r][c]=kv; v_s[r][c]=vv; }
    __syncthreads();
    for(int mm=sub; mm<kn; mm+=4){
      float l=0.f;
      #pragma unroll
      for(int c=0;c<16;c++) l += q_s[qi][c]*k_s[mm][c];
      l *= 0.25f;
      float newm = fmaxf(m,l);
      float e = __expf(l - newm);
      if(newm > m){
        float rr = __expf(m - newm);
        s *= rr;
        #pragma unroll
        for(int c=0;c<16;c++) acc[c]*=rr;
        m = newm;
      }
      s += e;
      #pragma unroll
      for(int c=0;c<16;c++) acc[c] += e*v_s[mm][c];
    }
  }
  red[sub][qi][0]=m; red[sub][qi][1]=s;
  #pragma unroll
  for(int c=0;c<16;c++) red[sub][qi][2+c]=acc[c];
  __syncthreads();
  if(sub==0){
    int n = qn_s[qi];
    if(n>=0){
      float M=-1e30f;
      #pragma unroll
      for(int j=0;j<4;j++) M=fmaxf(M,red[j][qi][0]);
      float S=0.f; float o[16];
      #pragma unroll
      for(int c=0;c<16;c++) o[c]=0.f;
      #pragma unroll
      for(int j=0;j<4;j++){ float e=__expf(red[j][qi][0]-M); S += e*red[j][qi][1];
        #pragma unroll
        for(int c=0;c<16;c++) o[c] += e*red[j][qi][2+c]; }
      float inv = 1.f/S;
      #pragma unroll
      for(int c=0;c<16;c++) att[((size_t)b*NQ+n)*128 + h*16 + c] = o[c]*inv;
    }
  }
}

// ---------------- proj + residual + LN (optional qc=ln_out+qpe) ----------------
template<bool WQC>
__global__ void k_proj_ln(const float* __restrict__ in, const float* __restrict__ W,
                          const float* __restrict__ bias, const float* __restrict__ resid,
                          const float* __restrict__ g, const float* __restrict__ bb,
                          const float* __restrict__ qpe, float* __restrict__ xout,
                          float* __restrict__ qc){
  int r0 = blockIdx.x*8; int d = threadIdx.x;
  __shared__ float s_in[8][128];
  __shared__ float s_m[8][2][2];
  for(int i=d;i<8*128;i+=128){ int r=i>>7, c=i&127; s_in[r][c] = in[(size_t)(r0+r)*128 + c]; }
  __syncthreads();
  float acc[8];
  #pragma unroll
  for(int r=0;r<8;r++) acc[r]=bias[d];
  #pragma unroll 4
  for(int c=0;c<128;c++){ float wv = W[c*128+d];
    #pragma unroll
    for(int r=0;r<8;r++) acc[r] += s_in[r][c]*wv; }
  float v[8];
  int lane = d&63, wid = d>>6;
  #pragma unroll
  for(int r=0;r<8;r++){
    v[r] = acc[r] + resid[(size_t)(r0+r)*128 + d];
    float s1=v[r], s2=v[r]*v[r];
    for(int o=32;o>0;o>>=1){ s1 += __shfl_down(s1,o); s2 += __shfl_down(s2,o); }
    if(lane==0){ s_m[r][wid][0]=s1; s_m[r][wid][1]=s2; }
  }
  __syncthreads();
  #pragma unroll
  for(int r=0;r<8;r++){
    float S1=s_m[r][0][0]+s_m[r][1][0], S2=s_m[r][0][1]+s_m[r][1][1];
    float mean=S1*(1.f/128.f), var=S2*(1.f/128.f)-mean*mean;
    float rs=rsqrtf(var+1e-5f);
    float o=(v[r]-mean)*rs*g[d]+bb[d];
    xout[(size_t)(r0+r)*128+d]=o;
    if(WQC) qc[(size_t)(r0+r)*128+d]=o+qpe[(size_t)(r0+r)*128+d];
  }
}

// ---------------- attn-weight matvec + per-head softmax(16) ----------------
__global__ void k_aw(const float* __restrict__ qc, const float* __restrict__ W,
                     const float* __restrict__ bias, float* __restrict__ aw){
  int r0 = blockIdx.x*8; int d = threadIdx.x;
  __shared__ float s_in[8][128];
  __shared__ float s_out[8][130];
  for(int i=d;i<8*128;i+=128){ int r=i>>7, c=i&127; s_in[r][c]=qc[(size_t)(r0+r)*128+c]; }
  __syncthreads();
  float acc[8];
  #pragma unroll
  for(int r=0;r<8;r++) acc[r]=bias[d];
  #pragma unroll 4
  for(int c=0;c<128;c++){ float wv = W[c*128+d];
    #pragma unroll
    for(int r=0;r<8;r++) acc[r] += s_in[r][c]*wv; }
  #pragma unroll
  for(int r=0;r<8;r++) s_out[r][d]=acc[r];
  __syncthreads();
  if(d < 64){
    int r = d>>3, h = d&7;
    float mx=-1e30f;
    #pragma unroll
    for(int i=0;i<16;i++) mx = fmaxf(mx, s_out[r][h*16+i]);
    float e[16]; float sm=0.f;
    #pragma unroll
    for(int i=0;i<16;i++){ e[i]=__expf(s_out[r][h*16+i]-mx); sm+=e[i]; }
    float inv = 1.f/sm;
    #pragma unroll
    for(int i=0;i<16;i++) aw[(size_t)(r0+r)*128 + h*16+i] = e[i]*inv;
  }
}

// ---------------- deformable bilinear sampling ----------------
__global__ void k_sample(const float* __restrict__ qpos, const int* __restrict__ view,
                         const float* __restrict__ offb, const float* __restrict__ awb,
                         const unsigned short* __restrict__ value, float* __restrict__ ca){
  int n = blockIdx.x, b = blockIdx.y;
  size_t row = (size_t)b*NQ + n;
  int t = threadIdx.x;
  int h = t>>4, lp = t&15, lvl = lp>>2;
  float rx = sigm(qpos[row*2]), ry = sigm(qpos[row*2+1]);
  int vw = view[row];
  int w = c_W[lvl], hh = c_H[lvl];
  float ox = offb[row*256 + t*2], oy = offb[row*256 + t*2+1];
  float a = awb[row*128 + t];
  float lx = rx*(float)w + ox - 0.5f;
  float ly = ry*(float)hh + oy - 0.5f;
  float x0f = floorf(lx), y0f = floorf(ly);
  float fx = lx - x0f, fy = ly - y0f;
  int x0 = (int)x0f, y0 = (int)y0f;
  float samp[16];
  #pragma unroll
  for(int c=0;c<16;c++) samp[c]=0.f;
  size_t brow = ((size_t)(b*VV + vw))*LTOT + c_S[lvl];
  #pragma unroll
  for(int dy=0;dy<2;dy++){
    #pragma unroll
    for(int dx=0;dx<2;dx++){
      int xi=x0+dx, yi=y0+dy;
      if(xi<0||xi>=w||yi<0||yi>=hh) continue;
      float wt = (dx?fx:(1.f-fx))*(dy?fy:(1.f-fy));
      const uint4* vp = reinterpret_cast<const uint4*>(value + (brow + (size_t)yi*w + xi)*CC + h*16);
      uint4 u0 = vp[0], u1 = vp[1];
      samp[0] += wt*bflo(u0.x); samp[1] += wt*bfhi(u0.x);
      samp[2] += wt*bflo(u0.y); samp[3] += wt*bfhi(u0.y);
      samp[4] += wt*bflo(u0.z); samp[5] += wt*bfhi(u0.z);
      samp[6] += wt*bflo(u0.w); samp[7] += wt*bfhi(u0.w);
      samp[8] += wt*bflo(u1.x); samp[9] += wt*bfhi(u1.x);
      samp[10]+= wt*bflo(u1.y); samp[11]+= wt*bfhi(u1.y);
      samp[12]+= wt*bflo(u1.z); samp[13]+= wt*bfhi(u1.z);
      samp[14]+= wt*bflo(u1.w); samp[15]+= wt*bfhi(u1.w);
    }
  }
  __shared__ float sred[128][17];
  #pragma unroll
  for(int c=0;c<16;c++) sred[t][c] = a*samp[c];
  __syncthreads();
  int h2=t>>4, c2=t&15;
  float sum=0.f;
  #pragma unroll
  for(int j=0;j<16;j++) sum += sred[h2*16+j][c2];
  ca[row*128 + t] = sum;
}

// ---------------- FFN2 + LN3 + valid-zero + out0 transpose ----------------
__global__ void k_ffn2_ln3(const float* __restrict__ hin, const float* __restrict__ W,
                           const float* __restrict__ bias, const float* __restrict__ resid,
                           const float* __restrict__ g, const float* __restrict__ bb,
                           const int* __restrict__ counts, const int* __restrict__ view,
                           float* __restrict__ xf, float* __restrict__ out0){
  int r0 = blockIdx.x*8; int d = threadIdx.x;
  __shared__ float s_in[8][256];
  __shared__ float s_m[8][2][2];
  for(int i=d;i<8*256;i+=128){ int r=i>>8, c=i&255; s_in[r][c]=hin[(size_t)(r0+r)*256+c]; }
  __syncthreads();
  float acc[8];
  #pragma unroll
  for(int r=0;r<8;r++) acc[r]=bias[d];
  #pragma unroll 4
  for(int c=0;c<256;c++){ float wv = W[c*128+d];
    #pragma unroll
    for(int r=0;r<8;r++) acc[r] += s_in[r][c]*wv; }
  float v[8];
  int lane = d&63, wid = d>>6;
  #pragma unroll
  for(int r=0;r<8;r++){
    v[r] = acc[r] + resid[(size_t)(r0+r)*128 + d];
    float s1=v[r], s2=v[r]*v[r];
    for(int o=32;o>0;o>>=1){ s1 += __shfl_down(s1,o); s2 += __shfl_down(s2,o); }
    if(lane==0){ s_m[r][wid][0]=s1; s_m[r][wid][1]=s2; }
  }
  __syncthreads();
  #pragma unroll
  for(int r=0;r<8;r++){
    float S1=s_m[r][0][0]+s_m[r][1][0], S2=s_m[r][0][1]+s_m[r][1][1];
    float mean=S1*(1.f/128.f), var=S2*(1.f/128.f)-mean*mean;
    float rs=rsqrtf(var+1e-5f);
    float o=(v[r]-mean)*rs*g[d]+bb[d];
    int row=r0+r; int b=row/NQ, n=row%NQ;
    bool val = counts[b*VV + view[row]] > 1;
    float oz = val ? o : 0.f;
    xf[(size_t)row*128+d]=oz;
    out0[((size_t)b*CC + d)*NQ + n]=oz;
  }
}

// ---------------- prediction head ----------------
__global__ void k_head(const float* __restrict__ xf, const float* __restrict__ pos,
                       const float* __restrict__ w1, const float* __restrict__ b1,
                       const float* __restrict__ w2, const float* __restrict__ b2,
                       float* __restrict__ dout){
  int row = blockIdx.x; int b=row/NQ, n=row%NQ; int t=threadIdx.x;
  __shared__ float xs[128];
  __shared__ float hid[128];
  __shared__ float res[6];
  xs[t] = xf[(size_t)row*128+t];
  __syncthreads();
  float a = b1[t];
  #pragma unroll 4
  for(int c=0;c<128;c++) a += xs[c]*w1[c*128+t];
  hid[t]=fmaxf(a,0.f);
  __syncthreads();
  if(t<6){ float a2=b2[t];
    #pragma unroll 4
    for(int c=0;c<128;c++) a2 += hid[c]*w2[c*6+t];
    res[t]=a2; }
  __syncthreads();
  if(t==0){
    const int O1 = BB*CC*NQ;            // 307200
    const int O2 = O1 + BB*NQ*2;        // 312000
    const int O3 = O2 + BB*2*NQ;        // 316800
    const int O4 = O3 + BB*4*NQ;        // 326400
    float p0=pos[row*2], p1=pos[row*2+1];
    float cr0 = res[0]+p0, cr1 = res[1]+p1;
    dout[O1 + row*2]   = cr0;
    dout[O1 + row*2+1] = cr1;
    float cen0 = sigm(cr0), cen1 = sigm(cr1);
    dout[O2 + (b*2+0)*NQ + n] = cen0;
    dout[O2 + (b*2+1)*NQ + n] = cen1;
    float f0=sigm(res[2]), f1=sigm(res[3]), f2=sigm(res[4]), f3=sigm(res[5]);
    dout[O3 + (b*4+0)*NQ + n] = f0;
    dout[O3 + (b*4+1)*NQ + n] = f1;
    dout[O3 + (b*4+2)*NQ + n] = f2;
    dout[O3 + (b*4+3)*NQ + n] = f3;
    float bw=f0+f2, bh=f1+f3;
    float cx=(2.f*cen0 - f0 + f2)*0.5f;
    float cy=(2.f*cen1 - f1 + f3)*0.5f;
    dout[O4 + (b*4+0)*NQ + n] = cx;
    dout[O4 + (b*4+1)*NQ + n] = cy;
    dout[O4 + (b*4+2)*NQ + n] = bw;
    dout[O4 + (b*4+3)*NQ + n] = bh;
  }
}

extern "C" void kernel_launch(void* const* d_in, const int* in_sizes, int n_in,
                              void* d_out, int out_size, void* d_ws, size_t ws_size,
                              hipStream_t stream){
  (void)in_sizes; (void)n_in; (void)out_size; (void)ws_size;
  const float* in_iqf  = (const float*)d_in[0];
  const float* in_qpos = (const float*)d_in[1];
  const float* in_feat[4] = {(const float*)d_in[2],(const float*)d_in[3],(const float*)d_in[4],(const float*)d_in[5]};
  const float* in_kpos = (const float*)d_in[6];
  const float* sp_w1=(const float*)d_in[7], *sp_b1=(const float*)d_in[8], *sp_w2=(const float*)d_in[9], *sp_b2=(const float*)d_in[10];
  const float* cp_w1=(const float*)d_in[11], *cp_b1=(const float*)d_in[12], *cp_w2=(const float*)d_in[13], *cp_b2=(const float*)d_in[14];
  const float* sa_wqkv=(const float*)d_in[15], *sa_bqkv=(const float*)d_in[16], *sa_wo=(const float*)d_in[17], *sa_bo=(const float*)d_in[18];
  const float* ln1_g=(const float*)d_in[19], *ln1_b=(const float*)d_in[20];
  const float* dvw=(const float*)d_in[21], *dvb=(const float*)d_in[22];
  const float* dow=(const float*)d_in[23], *dob=(const float*)d_in[24];
  const float* daw=(const float*)d_in[25], *dab=(const float*)d_in[26];
  const float* dOw=(const float*)d_in[27], *dOb=(const float*)d_in[28];
  const float* ln2_g=(const float*)d_in[29], *ln2_b=(const float*)d_in[30];
  const float* fw1=(const float*)d_in[31], *fb1=(const float*)d_in[32], *fw2=(const float*)d_in[33], *fb2=(const float*)d_in[34];
  const float* ln3_g=(const float*)d_in[35], *ln3_b=(const float*)d_in[36];
  const float* pw1=(const float*)d_in[37], *pb1=(const float*)d_in[38], *pw2=(const float*)d_in[39], *pb2=(const float*)d_in[40];
  const int* in_view = (const int*)d_in[41];
  float* out = (float*)d_out;

  char* ws = (char*)d_ws;
  unsigned short* value = (unsigned short*)ws;                       // 91,392,000 B
  unsigned short* kvpe  = (unsigned short*)(ws + 91392000);          //  7,616,000 B
  float* f = (float*)(ws + 91392000 + 7616000);
  float* qpe  = f;               // 307200
  float* x    = f + 307200;      // 307200
  float* qkv  = f + 614400;      // 921600
  float* att  = f + 1536000;     // 307200
  float* qc   = f + 1843200;     // 307200
  float* offb = f + 2150400;     // 614400
  float* awb  = f + 2764800;     // 307200
  float* ca   = f + 3072000;     // 307200
  float* ffnh = f + 3379200;     // 614400
  float* xf   = f + 3993600;     // 307200
  int* counts = (int*)(f + 4300800);   // 16 ints
  int* order  = (int*)(f + 4300816);   // B*VV*NQ = 14400 ints

  k_bucket<<<dim3(BB),dim3(64),0,stream>>>(in_view, order, counts);
  k_prep<<<dim3(NROWS),dim3(128),0,stream>>>(in_iqf,in_qpos,sp_w1,sp_b1,sp_w2,sp_b2,x,qpe);
  k_kvpe<<<dim3((LTOT+15)/16),dim3(256),0,stream>>>(in_kpos,cp_w1,cp_b1,cp_w2,cp_b2,dvw,dvb,kvpe);
  k_value_mfma<<<dim3(233, BB*VV),dim3(256),0,stream>>>(in_feat[0],in_feat[1],in_feat[2],in_feat[3],kvpe,dvw,value);
  k_matvec<128,384,8,false><<<dim3(NROWS/8),dim3(384),0,stream>>>(x,qpe,sa_wqkv,sa_bqkv,qkv,NROWS);
  k_attn_v<<<dim3((NQ+QT2-1)/QT2, VV*HH, BB),dim3(256),0,stream>>>(qkv,order,counts,att);
  k_proj_ln<true><<<dim3(NROWS/8),dim3(128),0,stream>>>(att,sa_wo,sa_bo,x,ln1_g,ln1_b,qpe,x,qc);
  k_matvec<128,256,8,false><<<dim3(NROWS/8),dim3(256),0,stream>>>(qc,nullptr,dow,dob,offb,NROWS);
  k_aw<<<dim3(NROWS/8),dim3(128),0,stream>>>(qc,daw,dab,awb);
  k_sample<<<dim3(NQ,BB),dim3(128),0,stream>>>(in_qpos,in_view,offb,awb,value,ca);
  k_proj_ln<false><<<dim3(NROWS/8),dim3(128),0,stream>>>(ca,dOw,dOb,x,ln2_g,ln2_b,nullptr,x,nullptr);
  k_matvec<128,256,8,true><<<dim3(NROWS/8),dim3(256),0,stream>>>(x,nullptr,fw1,fb1,ffnh,NROWS);
  k_ffn2_ln3<<<dim3(NROWS/8),dim3(128),0,stream>>>(ffnh,fw2,fb2,x,ln3_g,ln3_b,counts,in_view,xf,out);
  k_head<<<dim3(NROWS),dim3(128),0,stream>>>(xf,in_qpos,pw1,pb1,pw2,pb2,out);
}